// Round 12
// baseline (299.019 us; speedup 1.0000x reference)
//
#include <hip/hip_runtime.h>
#include <hip/hip_bf16.h>

typedef short  short8  __attribute__((ext_vector_type(8)));
typedef float  float4v __attribute__((ext_vector_type(4)));
typedef uint   uint4v  __attribute__((ext_vector_type(4)));

#define N_ROWS 4096
#define DDIM   64
#define NKB    (N_ROWS / 64)
#define SPLIT  16              // key-splits (grid.y); 4 key-blocks each
#define KBPB   (NKB / SPLIT)   // key-blocks per block = 4
#define HSTEP  0.125f
#define SIG0   0.001f

__device__ __forceinline__ ushort f2bf(float f) {
    __hip_bfloat16 h = __float2bfloat16(f);
    return *reinterpret_cast<ushort*>(&h);
}
__device__ __forceinline__ float bf2f(ushort u) {
    return __uint_as_float(((unsigned)u) << 16);
}
__device__ __forceinline__ float4v mfma16(short8 a, short8 b, float4v c) {
    return __builtin_amdgcn_mfma_f32_16x16x32_bf16(a, b, c, 0, 0, 0);
}

// ---------------------------------------------------------------------------
// x0 stats: x0sq[m] = ||x0_m||^2, x0sum[d] = sum_m x0[m][d]
// ---------------------------------------------------------------------------
__global__ __launch_bounds__(256) void x0stats_kernel(
    const float* __restrict__ x0, float* __restrict__ x0sq,
    float* __restrict__ x0sum)
{
    __shared__ float cs[64];
    const int tid = threadIdx.x;
    if (tid < 64) cs[tid] = 0.f;
    __syncthreads();
    const int r  = blockIdx.x * 64 + (tid >> 2);
    const int c0 = (tid & 3) * 16;
    const float4* rp = (const float4*)(x0 + (size_t)r * DDIM + c0);
    float f[16];
    float ss = 0.f;
#pragma unroll
    for (int k = 0; k < 4; ++k) {
        float4 v = rp[k];
        f[4 * k] = v.x; f[4 * k + 1] = v.y; f[4 * k + 2] = v.z; f[4 * k + 3] = v.w;
        ss += v.x * v.x + v.y * v.y + v.z * v.z + v.w * v.w;
    }
    ss += __shfl_xor(ss, 1, 64);
    ss += __shfl_xor(ss, 2, 64);
    if ((tid & 3) == 0) x0sq[r] = ss;
#pragma unroll
    for (int j = 0; j < 16; ++j) atomicAdd(&cs[c0 + j], f[j]);
    __syncthreads();
    if (tid < 64) atomicAdd(&x0sum[tid], cs[tid]);
}

// ---------------------------------------------------------------------------
// Pre-pack x0 into MFMA-fragment order (hi/lo split bf16) — R6 proven layout.
// Apk[kb][ks][half][lane]: lane(g,qi) holds x0[kb*64+ks*16+qi][half*32+g*8+j].
// Bpk[kb][ks2][dsub][lane]: lane(g,qi) holds x0[kb*64+ks2*32+g*8+j][dsub*16+qi].
// Per-kb: each array is 512 contiguous short8 (8KB) -> block-stageable.
// ---------------------------------------------------------------------------
__global__ __launch_bounds__(256) void prep_pack_kernel(
    const float* __restrict__ x0,
    short8* __restrict__ Apk_h, short8* __restrict__ Apk_l,
    short8* __restrict__ Bpk_h, short8* __restrict__ Bpk_l)
{
    __shared__ float xt_[64][65];
    const int tid  = threadIdx.x;
    const int kb64 = blockIdx.x;
    {
        const int r = tid >> 2, c0 = (tid & 3) * 16;
        const float4* src = (const float4*)(x0 + ((size_t)(kb64 * 64 + r)) * DDIM + c0);
#pragma unroll
        for (int k = 0; k < 4; ++k) {
            float4 v = src[k];
            xt_[r][c0 + 4 * k + 0] = v.x; xt_[r][c0 + 4 * k + 1] = v.y;
            xt_[r][c0 + 4 * k + 2] = v.z; xt_[r][c0 + 4 * k + 3] = v.w;
        }
    }
    __syncthreads();
    const int w = tid >> 6, lane = tid & 63, qi = lane & 15, g = lane >> 4;
#pragma unroll
    for (int half = 0; half < 2; ++half) {
        short8 h, l;
#pragma unroll
        for (int j = 0; j < 8; ++j) {
            float v = xt_[w * 16 + qi][half * 32 + g * 8 + j];
            ushort hh = f2bf(v);
            h[j] = (short)hh;
            l[j] = (short)f2bf(v - bf2f(hh));
        }
        size_t idx = (((size_t)kb64 * 4 + w) * 2 + half) * 64 + lane;
        Apk_h[idx] = h; Apk_l[idx] = l;
    }
#pragma unroll
    for (int pp = 0; pp < 2; ++pp) {
        int pw = w + pp * 4;
        int ks2 = pw >> 2, dsub = pw & 3;
        short8 h, l;
#pragma unroll
        for (int j = 0; j < 8; ++j) {
            float v = xt_[ks2 * 32 + g * 8 + j][dsub * 16 + qi];
            ushort hh = f2bf(v);
            h[j] = (short)hh;
            l[j] = (short)f2bf(v - bf2f(hh));
        }
        size_t idx = (((size_t)kb64 * 2 + ks2) * 4 + dsub) * 64 + lane;
        Bpk_h[idx] = h; Bpk_l[idx] = l;
    }
}

// ---------------------------------------------------------------------------
// G(t=1) closed form: scores are exactly 0 -> qt = mean(x0); sigma=1
// ---------------------------------------------------------------------------
__global__ __launch_bounds__(256) void g1_init_kernel(
    const float* __restrict__ z, const float* __restrict__ x0sum,
    float* __restrict__ G1)
{
    int i = blockIdx.x * 256 + threadIdx.x;
    G1[i] = (1.0f - SIG0) * z[i] - x0sum[i & 63] * (1.0f / 4096.0f);
}

// ---------------------------------------------------------------------------
// Flash partial pass (R12): grid (16 row-blocks, 16 key-splits) = 256 blocks.
// Block = 1024 thr = 16 waves; wave w owns rows [bx*256+w*16, +16); ALL waves
// share this block's 4 key-blocks, whose fragments (128KB) are staged in LDS
// once. Cuts L2 fragment traffic 16x vs R11 (512MB -> 32MB per pass).
// Inner loop = proven R6/R11 math (QK 6-term, PV 3-term split-precision).
// ---------------------------------------------------------------------------
__global__ __launch_bounds__(1024) void g_partial_kernel(
    const float* __restrict__ xt, const float* __restrict__ G1, float c2,
    const short8* __restrict__ Apk_h, const short8* __restrict__ Apk_l,
    const short8* __restrict__ Bpk_h, const short8* __restrict__ Bpk_l,
    const float* __restrict__ x0sq, float scale, float beta,
    float* __restrict__ o_part, float* __restrict__ m_part,
    float* __restrict__ l_part)
{
    __shared__ short8 lAh[KBPB * 512];   // 32KB each, 128KB total (gfx950 OK)
    __shared__ short8 lAl[KBPB * 512];
    __shared__ short8 lBh[KBPB * 512];
    __shared__ short8 lBl[KBPB * 512];

    const int tid  = threadIdx.x;
    const int w    = tid >> 6;
    const int lane = tid & 63;
    const int g    = lane >> 4;
    const int qi   = lane & 15;
    const int bx   = blockIdx.x;
    const int split = blockIdx.y;
    const int kb0  = split * KBPB;               // first key-block
    const int row  = bx * 256 + w * 16 + qi;     // wave-private rows

    // ---- stage this split's fragments into LDS (2 short8 per thread/array) ----
    {
        const short8* gA = Apk_h + (size_t)kb0 * 512;
        const short8* ga = Apk_l + (size_t)kb0 * 512;
        const short8* gB = Bpk_h + (size_t)kb0 * 512;
        const short8* gb = Bpk_l + (size_t)kb0 * 512;
#pragma unroll
        for (int i = 0; i < 2; ++i) {
            int idx = tid + i * 1024;
            lAh[idx] = gA[idx];
            lAl[idx] = ga[idx];
            lBh[idx] = gB[idx];
            lBl[idx] = gb[idx];
        }
    }

    // ---- x B-frags for this lane's query row: d = ds*32 + g*8 + j ----
    short8 xbh[2], xbl[2];
    {
        const float* a = xt + (size_t)row * DDIM;
        const float* b = G1 + (size_t)row * DDIM;
#pragma unroll
        for (int ds_ = 0; ds_ < 2; ++ds_) {
            const int d0 = ds_ * 32 + g * 8;
#pragma unroll
            for (int j = 0; j < 8; ++j) {
                float x = a[d0 + j] + c2 * b[d0 + j];
                ushort h = f2bf(x);
                xbh[ds_][j] = (short)h;
                xbl[ds_][j] = (short)f2bf(x - bf2f(h));
            }
        }
    }
    __syncthreads();   // staged fragments visible

    float4v pvacc[4];
#pragma unroll
    for (int d = 0; d < 4; ++d) pvacc[d] = (float4v){0.f, 0.f, 0.f, 0.f};
    float m = -1.0e30f, lsum = 0.f;

    for (int kbl = 0; kbl < KBPB; ++kbl) {
        const int kb = (kb0 + kbl) * 64;

        // ---- QK^T: scores sc[ks][r], key = kb + ks*16 + g*4 + r ----
        float sc[4][4];
#pragma unroll
        for (int ks = 0; ks < 4; ++ks) {
            const int ai = ((kbl * 4 + ks) * 2) * 64 + lane;
            short8 Ah0 = lAh[ai];
            short8 Ah1 = lAh[ai + 64];
            short8 Al0 = lAl[ai];
            short8 Al1 = lAl[ai + 64];
            float4v acc = (float4v){0.f, 0.f, 0.f, 0.f};
            __builtin_amdgcn_s_setprio(1);
            acc = mfma16(Ah0, xbh[0], acc);
            acc = mfma16(Ah1, xbh[1], acc);
            acc = mfma16(Al0, xbh[0], acc);
            acc = mfma16(Al1, xbh[1], acc);
            acc = mfma16(Ah0, xbl[0], acc);
            acc = mfma16(Ah1, xbl[1], acc);
            __builtin_amdgcn_s_setprio(0);
            const float4 sq = *(const float4*)(x0sq + kb + ks * 16 + g * 4);
            sc[ks][0] = scale * acc[0] - beta * sq.x;
            sc[ks][1] = scale * acc[1] - beta * sq.y;
            sc[ks][2] = scale * acc[2] - beta * sq.z;
            sc[ks][3] = scale * acc[3] - beta * sq.w;
        }

        // ---- online softmax ----
        float tmax = sc[0][0];
#pragma unroll
        for (int ks = 0; ks < 4; ++ks)
#pragma unroll
            for (int r = 0; r < 4; ++r) tmax = fmaxf(tmax, sc[ks][r]);
        tmax = fmaxf(tmax, __shfl_xor(tmax, 16, 64));
        tmax = fmaxf(tmax, __shfl_xor(tmax, 32, 64));
        const float mn = fmaxf(m, tmax);
        const float co = __expf(m - mn);
        float psum = 0.f;
#pragma unroll
        for (int ks = 0; ks < 4; ++ks)
#pragma unroll
            for (int r = 0; r < 4; ++r) {
                sc[ks][r] = __expf(sc[ks][r] - mn);   // sc now holds p
                psum += sc[ks][r];
            }
        psum += __shfl_xor(psum, 16, 64);
        psum += __shfl_xor(psum, 32, 64);
        lsum = lsum * co + psum;
        m = mn;
        float co_r[4];
#pragma unroll
        for (int r = 0; r < 4; ++r) co_r[r] = __shfl(co, g * 4 + r, 64);
#pragma unroll
        for (int d = 0; d < 4; ++d)
#pragma unroll
            for (int r = 0; r < 4; ++r) pvacc[d][r] *= co_r[r];

        // ---- pack P hi/lo: pk[ks][pr] = keys (ks*16 + g*4 + 2pr, +1) ----
        uint pkh[4][2], pkl[4][2];
#pragma unroll
        for (int ks = 0; ks < 4; ++ks)
#pragma unroll
            for (int pr = 0; pr < 2; ++pr) {
                float f0 = sc[ks][2 * pr], f1 = sc[ks][2 * pr + 1];
                ushort h0 = f2bf(f0), h1 = f2bf(f1);
                pkh[ks][pr] = (uint)h0 | ((uint)h1 << 16);
                ushort e0 = f2bf(f0 - bf2f(h0)), e1 = f2bf(f1 - bf2f(h1));
                pkl[ks][pr] = (uint)e0 | ((uint)e1 << 16);
            }

        // ---- PV per 32-key step: shfl relayout, 3-term MFMA ----
#pragma unroll
        for (int ks2 = 0; ks2 < 2; ++ks2) {
            uint4v pah, pal;
#pragma unroll
            for (int c = 0; c < 4; ++c) {
                const int src = (2 * (g & 1) + (c >> 1)) * 16 + qi;
                uint h0 = (uint)__shfl((int)pkh[2 * ks2][c & 1], src, 64);
                uint h1 = (uint)__shfl((int)pkh[2 * ks2 + 1][c & 1], src, 64);
                pah[c] = (g >= 2) ? h1 : h0;
                uint l0 = (uint)__shfl((int)pkl[2 * ks2][c & 1], src, 64);
                uint l1 = (uint)__shfl((int)pkl[2 * ks2 + 1][c & 1], src, 64);
                pal[c] = (g >= 2) ? l1 : l0;
            }
            const short8 PAh = __builtin_bit_cast(short8, pah);
            const short8 PAl = __builtin_bit_cast(short8, pal);
#pragma unroll
            for (int dsub = 0; dsub < 4; ++dsub) {
                const int bi = ((kbl * 2 + ks2) * 4 + dsub) * 64 + lane;
                short8 Bh = lBh[bi];
                short8 Bl = lBl[bi];
                __builtin_amdgcn_s_setprio(1);
                pvacc[dsub] = mfma16(PAh, Bh, pvacc[dsub]);
                pvacc[dsub] = mfma16(PAh, Bl, pvacc[dsub]);
                pvacc[dsub] = mfma16(PAl, Bh, pvacc[dsub]);
                __builtin_amdgcn_s_setprio(0);
            }
        }
    }

    // ---- store partials: PV D row = q_local = g*4 + r, col d = dsub*16 + qi ----
    const int orow0 = bx * 256 + w * 16;
#pragma unroll
    for (int dsub = 0; dsub < 4; ++dsub)
#pragma unroll
        for (int r = 0; r < 4; ++r)
            o_part[((size_t)split * N_ROWS + orow0 + g * 4 + r) * DDIM + dsub * 16 + qi] =
                pvacc[dsub][r];
    if (g == 0) {
        m_part[split * N_ROWS + orow0 + qi] = m;
        l_part[split * N_ROWS + orow0 + qi] = lsum;
    }
}

// ---------------------------------------------------------------------------
// Combine partials -> qt -> G2; fused Heun update of xt. Wave per row, lane=d.
// (R6-proven, SPLIT=16 fully unrolled.)
// ---------------------------------------------------------------------------
__global__ __launch_bounds__(256) void combine_kernel(
    float* __restrict__ xt, const float* __restrict__ G1, float c2,
    const float* __restrict__ o_part, const float* __restrict__ m_part,
    const float* __restrict__ l_part, float inv_sig,
    float* __restrict__ G2out)
{
    const int tid = threadIdx.x;
    const int w = tid >> 6, lane = tid & 63;
    const int row = blockIdx.x * 4 + w;
    float mv[SPLIT];
#pragma unroll
    for (int i = 0; i < SPLIT; ++i) mv[i] = m_part[i * N_ROWS + row];
    float mstar = -1.0e30f;
#pragma unroll
    for (int i = 0; i < SPLIT; ++i) mstar = fmaxf(mstar, mv[i]);
    float L = 0.f, num = 0.f;
#pragma unroll
    for (int i = 0; i < SPLIT; ++i) {
        float e = __expf(mv[i] - mstar);
        L   += l_part[i * N_ROWS + row] * e;
        num += o_part[((size_t)i * N_ROWS + row) * DDIM + lane] * e;
    }
    const float qt = num / L;
    const size_t idx = (size_t)row * DDIM + lane;
    const float g1 = G1[idx];
    const float x  = xt[idx] + c2 * g1;
    const float g2 = ((1.0f - SIG0) * x - qt) * inv_sig;
    G2out[idx] = g2;
    xt[idx] -= (g1 + g2) * (HSTEP * 0.5f);
}

// ---------------------------------------------------------------------------
extern "C" void kernel_launch(void* const* d_in, const int* in_sizes, int n_in,
                              void* d_out, int out_size, void* d_ws, size_t ws_size,
                              hipStream_t stream) {
    const float* z  = (const float*)d_in[0];
    const float* x0 = (const float*)d_in[1];
    float* xt = (float*)d_out;

    // ---- workspace layout (256B aligned blocks); total ~45MB ----
    char* p = (char*)d_ws;
    auto alloc = [&](size_t bytes) {
        char* q = p; p += (bytes + 255) & ~(size_t)255; return q;
    };
    float*  G1    = (float*)alloc((size_t)N_ROWS * DDIM * 4);
    float*  G2    = (float*)alloc((size_t)N_ROWS * DDIM * 4);
    float*  x0sq  = (float*)alloc((size_t)N_ROWS * 4);
    float*  x0sum = (float*)alloc(64 * 4);
    short8* Apk_h = (short8*)alloc((size_t)NKB * 4 * 2 * 64 * 16);
    short8* Apk_l = (short8*)alloc((size_t)NKB * 4 * 2 * 64 * 16);
    short8* Bpk_h = (short8*)alloc((size_t)NKB * 2 * 4 * 64 * 16);
    short8* Bpk_l = (short8*)alloc((size_t)NKB * 2 * 4 * 64 * 16);
    float* o_part = (float*)alloc((size_t)SPLIT * N_ROWS * DDIM * 4);
    float* m_part = (float*)alloc((size_t)SPLIT * N_ROWS * 4);
    float* l_part = (float*)alloc((size_t)SPLIT * N_ROWS * 4);

    // ---- init: xt = z; x0 derived arrays; G1 = G(t=1) closed form ----
    hipMemcpyAsync(xt, z, (size_t)N_ROWS * DDIM * 4, hipMemcpyDeviceToDevice, stream);
    hipMemsetAsync(x0sum, 0, 64 * 4, stream);
    x0stats_kernel<<<NKB, 256, 0, stream>>>(x0, x0sq, x0sum);
    prep_pack_kernel<<<NKB, 256, 0, stream>>>(x0, Apk_h, Apk_l, Bpk_h, Bpk_l);
    g1_init_kernel<<<(N_ROWS * DDIM) / 256, 256, 0, stream>>>(z, x0sum, G1);

    // ---- 7 Heun steps ----
    for (int i = 0; i < 7; ++i) {
        float t  = (float)(7 - i) / 8.0f;
        float al = 1.0f - t;
        float sg = SIG0 + (1.0f - SIG0) * t;
        float scale = al / (sg * sg);
        float beta  = al * al / (2.0f * sg * sg);
        g_partial_kernel<<<dim3(N_ROWS / 256, SPLIT), 1024, 0, stream>>>(
            xt, G1, -HSTEP, Apk_h, Apk_l, Bpk_h, Bpk_l, x0sq, scale, beta,
            o_part, m_part, l_part);
        combine_kernel<<<N_ROWS / 4, 256, 0, stream>>>(
            xt, G1, -HSTEP, o_part, m_part, l_part, 1.0f / sg, G2);
        float* tmp = G1; G1 = G2; G2 = tmp;
    }
}

// Round 13
// 212.570 us; speedup vs baseline: 1.4067x; 1.4067x over previous
//
#include <hip/hip_runtime.h>
#include <hip/hip_bf16.h>

typedef short  short8  __attribute__((ext_vector_type(8)));
typedef float  float4v __attribute__((ext_vector_type(4)));
typedef uint   uint4v  __attribute__((ext_vector_type(4)));

#define N_ROWS 4096
#define DDIM   64
#define NKB    (N_ROWS / 64)
#define NSPLIT 16              // wave = key-split; 16 waves/block
#define NT4    (NKB / NSPLIT)  // 4 key-blocks per wave per step
#define HSTEP  0.125f
#define SIG0   0.001f

__device__ __forceinline__ ushort f2bf(float f) {
    __hip_bfloat16 h = __float2bfloat16(f);
    return *reinterpret_cast<ushort*>(&h);
}
__device__ __forceinline__ float bf2f(ushort u) {
    return __uint_as_float(((unsigned)u) << 16);
}
__device__ __forceinline__ float4v mfma16(short8 a, short8 b, float4v c) {
    return __builtin_amdgcn_mfma_f32_16x16x32_bf16(a, b, c, 0, 0, 0);
}

// ---------------------------------------------------------------------------
// Prep (fused stats + pack): x0sq[m], x0sum[d], and MFMA-fragment packing
// (hi/lo split bf16, R6-proven layout).
// Apk[kb][ks][half][lane]: lane(g,qi) holds x0[kb*64+ks*16+qi][half*32+g*8+j].
// Bpk[kb][ks2][dsub][lane]: lane(g,qi) holds x0[kb*64+ks2*32+g*8+j][dsub*16+qi].
// R8 lesson: PV needs 3-term split too (iterated sharp-softmax amplifies).
// ---------------------------------------------------------------------------
__global__ __launch_bounds__(256) void prep_pack_kernel(
    const float* __restrict__ x0,
    short8* __restrict__ Apk_h, short8* __restrict__ Apk_l,
    short8* __restrict__ Bpk_h, short8* __restrict__ Bpk_l,
    float* __restrict__ x0sq, float* __restrict__ x0sum)
{
    __shared__ float xt_[64][65];
    __shared__ float cs[64];
    const int tid  = threadIdx.x;
    const int kb64 = blockIdx.x;
    if (tid < 64) cs[tid] = 0.f;
    __syncthreads();
    {
        const int r = tid >> 2, c0 = (tid & 3) * 16;
        const float4* src = (const float4*)(x0 + ((size_t)(kb64 * 64 + r)) * DDIM + c0);
        float ss = 0.f;
#pragma unroll
        for (int k = 0; k < 4; ++k) {
            float4 v = src[k];
            xt_[r][c0 + 4 * k + 0] = v.x; xt_[r][c0 + 4 * k + 1] = v.y;
            xt_[r][c0 + 4 * k + 2] = v.z; xt_[r][c0 + 4 * k + 3] = v.w;
            ss += v.x * v.x + v.y * v.y + v.z * v.z + v.w * v.w;
            atomicAdd(&cs[c0 + 4 * k + 0], v.x);
            atomicAdd(&cs[c0 + 4 * k + 1], v.y);
            atomicAdd(&cs[c0 + 4 * k + 2], v.z);
            atomicAdd(&cs[c0 + 4 * k + 3], v.w);
        }
        ss += __shfl_xor(ss, 1, 64);
        ss += __shfl_xor(ss, 2, 64);
        if ((tid & 3) == 0) x0sq[kb64 * 64 + r] = ss;
    }
    __syncthreads();
    if (tid < 64) atomicAdd(&x0sum[tid], cs[tid]);

    const int w = tid >> 6, lane = tid & 63, qi = lane & 15, g = lane >> 4;
#pragma unroll
    for (int half = 0; half < 2; ++half) {
        short8 h, l;
#pragma unroll
        for (int j = 0; j < 8; ++j) {
            float v = xt_[w * 16 + qi][half * 32 + g * 8 + j];
            ushort hh = f2bf(v);
            h[j] = (short)hh;
            l[j] = (short)f2bf(v - bf2f(hh));
        }
        size_t idx = (((size_t)kb64 * 4 + w) * 2 + half) * 64 + lane;
        Apk_h[idx] = h; Apk_l[idx] = l;
    }
#pragma unroll
    for (int pp = 0; pp < 2; ++pp) {
        int pw = w + pp * 4;
        int ks2 = pw >> 2, dsub = pw & 3;
        short8 h, l;
#pragma unroll
        for (int j = 0; j < 8; ++j) {
            float v = xt_[ks2 * 32 + g * 8 + j][dsub * 16 + qi];
            ushort hh = f2bf(v);
            h[j] = (short)hh;
            l[j] = (short)f2bf(v - bf2f(hh));
        }
        size_t idx = (((size_t)kb64 * 2 + ks2) * 4 + dsub) * 64 + lane;
        Bpk_h[idx] = h; Bpk_l[idx] = l;
    }
}

// ---------------------------------------------------------------------------
// Persistent flow kernel (R13): 256 blocks x 1024 thr; block owns 16 rows for
// ALL 7 Heun steps (rows depend only on themselves + constant x0 -> no grid
// sync needed). xt/G1 live in LDS across steps; G(t=1) init closed-form.
// Per step: wave w sweeps key-split w (4 key-blocks, R11-proven inner loop),
// partials to LDS, in-block combine + Heun update, barrier, next step.
// part[] stride 66 words: partial-store banks qi+8g -> exact 2-way (free).
// ---------------------------------------------------------------------------
__global__ __launch_bounds__(1024) void flow_kernel(
    const float* __restrict__ z, const float* __restrict__ x0sum,
    const short8* __restrict__ Apk_h, const short8* __restrict__ Apk_l,
    const short8* __restrict__ Bpk_h, const short8* __restrict__ Bpk_l,
    const float* __restrict__ x0sq, float* __restrict__ xt_out)
{
    __shared__ float xt_lds[16][65];
    __shared__ float G1_lds[16][65];
    __shared__ float part[NSPLIT][16][66];
    __shared__ float m_lds[NSPLIT][17];
    __shared__ float l_lds[NSPLIT][17];

    const int tid  = threadIdx.x;
    const int w    = tid >> 6;      // wave = key-split, 0..15
    const int lane = tid & 63;
    const int g    = lane >> 4;
    const int qi   = lane & 15;
    const int crow = tid >> 6;      // combine row
    const int d    = tid & 63;      // combine dim
    const int rowbase = blockIdx.x * 16;

    // ---- init: xt = z; G1 = G(t=1) closed form (scores==0 -> qt=mean(x0)) ----
    {
        float zv = z[(size_t)(rowbase + crow) * DDIM + d];
        xt_lds[crow][d] = zv;
        G1_lds[crow][d] = (1.0f - SIG0) * zv - x0sum[d] * (1.0f / 4096.0f);
    }
    __syncthreads();

    for (int step = 0; step < 7; ++step) {
        const float t  = (float)(7 - step) * 0.125f;
        const float al = 1.0f - t;
        const float sg = SIG0 + (1.0f - SIG0) * t;
        const float scale = al / (sg * sg);
        const float beta  = al * al / (2.0f * sg * sg);
        const float inv_sig = 1.0f / sg;

        // ---- x B-frags from LDS: x = xt - H*G1, d = ds*32 + g*8 + j ----
        short8 xbh[2], xbl[2];
#pragma unroll
        for (int ds_ = 0; ds_ < 2; ++ds_) {
            const int d0 = ds_ * 32 + g * 8;
#pragma unroll
            for (int j = 0; j < 8; ++j) {
                float x = xt_lds[qi][d0 + j] - HSTEP * G1_lds[qi][d0 + j];
                ushort h = f2bf(x);
                xbh[ds_][j] = (short)h;
                xbl[ds_][j] = (short)f2bf(x - bf2f(h));
            }
        }

        float4v pvacc[4];
#pragma unroll
        for (int dd = 0; dd < 4; ++dd) pvacc[dd] = (float4v){0.f, 0.f, 0.f, 0.f};
        float m = -1.0e30f, lsum = 0.f;

        for (int tile = 0; tile < NT4; ++tile) {
            const int kbi = w * NT4 + tile;
            const int kb  = kbi * 64;

            // ---- QK^T: sc[ks][r], key = kb + ks*16 + g*4 + r ----
            float sc[4][4];
#pragma unroll
            for (int ks = 0; ks < 4; ++ks) {
                const size_t ai = (((size_t)kbi * 4 + ks) * 2) * 64 + lane;
                short8 Ah0 = Apk_h[ai];
                short8 Ah1 = Apk_h[ai + 64];
                short8 Al0 = Apk_l[ai];
                short8 Al1 = Apk_l[ai + 64];
                float4v acc = (float4v){0.f, 0.f, 0.f, 0.f};
                __builtin_amdgcn_s_setprio(1);
                acc = mfma16(Ah0, xbh[0], acc);
                acc = mfma16(Ah1, xbh[1], acc);
                acc = mfma16(Al0, xbh[0], acc);
                acc = mfma16(Al1, xbh[1], acc);
                acc = mfma16(Ah0, xbl[0], acc);
                acc = mfma16(Ah1, xbl[1], acc);
                __builtin_amdgcn_s_setprio(0);
                const float4 sq = *(const float4*)(x0sq + kb + ks * 16 + g * 4);
                sc[ks][0] = scale * acc[0] - beta * sq.x;
                sc[ks][1] = scale * acc[1] - beta * sq.y;
                sc[ks][2] = scale * acc[2] - beta * sq.z;
                sc[ks][3] = scale * acc[3] - beta * sq.w;
            }

            // ---- online softmax ----
            float tmax = sc[0][0];
#pragma unroll
            for (int ks = 0; ks < 4; ++ks)
#pragma unroll
                for (int r = 0; r < 4; ++r) tmax = fmaxf(tmax, sc[ks][r]);
            tmax = fmaxf(tmax, __shfl_xor(tmax, 16, 64));
            tmax = fmaxf(tmax, __shfl_xor(tmax, 32, 64));
            const float mn = fmaxf(m, tmax);
            const float co = __expf(m - mn);
            float psum = 0.f;
#pragma unroll
            for (int ks = 0; ks < 4; ++ks)
#pragma unroll
                for (int r = 0; r < 4; ++r) {
                    sc[ks][r] = __expf(sc[ks][r] - mn);   // sc now holds p
                    psum += sc[ks][r];
                }
            psum += __shfl_xor(psum, 16, 64);
            psum += __shfl_xor(psum, 32, 64);
            lsum = lsum * co + psum;
            m = mn;
            float co_r[4];
#pragma unroll
            for (int r = 0; r < 4; ++r) co_r[r] = __shfl(co, g * 4 + r, 64);
#pragma unroll
            for (int dd = 0; dd < 4; ++dd)
#pragma unroll
                for (int r = 0; r < 4; ++r) pvacc[dd][r] *= co_r[r];

            // ---- pack P hi/lo ----
            uint pkh[4][2], pkl[4][2];
#pragma unroll
            for (int ks = 0; ks < 4; ++ks)
#pragma unroll
                for (int pr = 0; pr < 2; ++pr) {
                    float f0 = sc[ks][2 * pr], f1 = sc[ks][2 * pr + 1];
                    ushort h0 = f2bf(f0), h1 = f2bf(f1);
                    pkh[ks][pr] = (uint)h0 | ((uint)h1 << 16);
                    ushort e0 = f2bf(f0 - bf2f(h0)), e1 = f2bf(f1 - bf2f(h1));
                    pkl[ks][pr] = (uint)e0 | ((uint)e1 << 16);
                }

            // ---- PV per 32-key step: shfl relayout, 3-term MFMA ----
#pragma unroll
            for (int ks2 = 0; ks2 < 2; ++ks2) {
                uint4v pah, pal;
#pragma unroll
                for (int c = 0; c < 4; ++c) {
                    const int src = (2 * (g & 1) + (c >> 1)) * 16 + qi;
                    uint h0 = (uint)__shfl((int)pkh[2 * ks2][c & 1], src, 64);
                    uint h1 = (uint)__shfl((int)pkh[2 * ks2 + 1][c & 1], src, 64);
                    pah[c] = (g >= 2) ? h1 : h0;
                    uint l0 = (uint)__shfl((int)pkl[2 * ks2][c & 1], src, 64);
                    uint l1 = (uint)__shfl((int)pkl[2 * ks2 + 1][c & 1], src, 64);
                    pal[c] = (g >= 2) ? l1 : l0;
                }
                const short8 PAh = __builtin_bit_cast(short8, pah);
                const short8 PAl = __builtin_bit_cast(short8, pal);
#pragma unroll
                for (int dsub = 0; dsub < 4; ++dsub) {
                    const size_t bi = (((size_t)kbi * 2 + ks2) * 4 + dsub) * 64 + lane;
                    short8 Bh = Bpk_h[bi];
                    short8 Bl = Bpk_l[bi];
                    __builtin_amdgcn_s_setprio(1);
                    pvacc[dsub] = mfma16(PAh, Bh, pvacc[dsub]);
                    pvacc[dsub] = mfma16(PAh, Bl, pvacc[dsub]);
                    pvacc[dsub] = mfma16(PAl, Bh, pvacc[dsub]);
                    __builtin_amdgcn_s_setprio(0);
                }
            }
        }

        // ---- partials -> LDS: PV D row = g*4 + r, col d = dsub*16 + qi ----
#pragma unroll
        for (int dsub = 0; dsub < 4; ++dsub)
#pragma unroll
            for (int r = 0; r < 4; ++r)
                part[w][g * 4 + r][dsub * 16 + qi] = pvacc[dsub][r];
        if (g == 0) { m_lds[w][qi] = m; l_lds[w][qi] = lsum; }
        __syncthreads();

        // ---- in-block combine + Heun update (thread = (crow, d)) ----
        {
            float mstar = m_lds[0][crow];
#pragma unroll
            for (int i = 1; i < NSPLIT; ++i) mstar = fmaxf(mstar, m_lds[i][crow]);
            float L = 0.f, num = 0.f;
#pragma unroll
            for (int i = 0; i < NSPLIT; ++i) {
                float e = __expf(m_lds[i][crow] - mstar);
                L   += l_lds[i][crow] * e;
                num += part[i][crow][d] * e;
            }
            const float qt  = num / L;
            const float g1v = G1_lds[crow][d];
            const float xv  = xt_lds[crow][d] - HSTEP * g1v;
            const float g2  = ((1.0f - SIG0) * xv - qt) * inv_sig;
            xt_lds[crow][d] -= (g1v + g2) * (HSTEP * 0.5f);
            G1_lds[crow][d]  = g2;   // own cell only: no cross-thread hazard
        }
        __syncthreads();   // xt/G1 updates visible before next step's B-frags
    }

    // ---- final write ----
    xt_out[(size_t)(rowbase + crow) * DDIM + d] = xt_lds[crow][d];
}

// ---------------------------------------------------------------------------
extern "C" void kernel_launch(void* const* d_in, const int* in_sizes, int n_in,
                              void* d_out, int out_size, void* d_ws, size_t ws_size,
                              hipStream_t stream) {
    const float* z  = (const float*)d_in[0];
    const float* x0 = (const float*)d_in[1];
    float* xt = (float*)d_out;

    // ---- workspace layout (256B aligned); ~8.4MB ----
    char* p = (char*)d_ws;
    auto alloc = [&](size_t bytes) {
        char* q = p; p += (bytes + 255) & ~(size_t)255; return q;
    };
    float*  x0sq  = (float*)alloc((size_t)N_ROWS * 4);
    float*  x0sum = (float*)alloc(64 * 4);
    short8* Apk_h = (short8*)alloc((size_t)NKB * 4 * 2 * 64 * 16);
    short8* Apk_l = (short8*)alloc((size_t)NKB * 4 * 2 * 64 * 16);
    short8* Bpk_h = (short8*)alloc((size_t)NKB * 2 * 4 * 64 * 16);
    short8* Bpk_l = (short8*)alloc((size_t)NKB * 2 * 4 * 64 * 16);

    hipMemsetAsync(x0sum, 0, 64 * 4, stream);
    prep_pack_kernel<<<NKB, 256, 0, stream>>>(x0, Apk_h, Apk_l, Bpk_h, Bpk_l,
                                              x0sq, x0sum);
    flow_kernel<<<N_ROWS / 16, 1024, 0, stream>>>(z, x0sum, Apk_h, Apk_l,
                                                  Bpk_h, Bpk_l, x0sq, xt);
}